// Round 1
// baseline (141.341 us; speedup 1.0000x reference)
//
#include <hip/hip_runtime.h>
#include <math.h>

// Problem constants (fixed by setup_inputs)
constexpr int Bc   = 32768;
constexpr int NAc  = 60;

constexpr int BPB  = 4;                    // batch elems per group (1 per wave)
constexpr int PBLK = 2048;                 // persistent blocks (grid size)
constexpr int ITER = Bc / (BPB * PBLK);    // 4 groups per block
constexpr int ROWF = NAc * 9;              // 540 floats of gt_R per b
constexpr int GRPF = BPB * ROWF;           // 2160 floats per group tile (8640 B)

// cos(1.0 rad): mask (gt_bias < 1) <=> clip(0.5*(tr-1)) > cos(1)
#define COS_ONE 0.5403023058681398f

typedef const __attribute__((address_space(1))) void* as1cv;
typedef __attribute__((address_space(3)))       void* as3v;

// Async-stage one group tile (8192 B of 8640) direct to LDS: per wave two
// 1 KiB chunks, lane*16B on the GLOBAL side, wave-uniform LDS base.
// Remaining 448 B handled by the caller via reg-split (load early, write late).
__device__ __forceinline__ void stage_group_async(const float* __restrict__ gt_R,
                                                  int grp, float* lds,
                                                  int wave, int lane)
{
    const float* gbase = gt_R + (size_t)grp * GRPF;
    const int woff = wave * 512;                       // floats (2048 B / wave)
    __builtin_amdgcn_global_load_lds((as1cv)(gbase + woff + lane * 4),
                                     (as3v)(lds + woff), 16, 0, 0);
    __builtin_amdgcn_global_load_lds((as1cv)(gbase + woff + 256 + lane * 4),
                                     (as3v)(lds + woff + 256), 16, 0, 0);
}

// ---------------------------------------------------------------------------
// Persistent fused kernel: each block owns ITER groups of 4 batch elems
// (1 per wave). LDS double-buffer: group it+1's gt_R staged asynchronously
// (global_load_lds) while group it computes; drained by the one barrier per
// iteration. wts/y/label reg-prefetched. l2/logp/correct accumulate in
// registers across groups; one cross-wave reduction per block.
// ---------------------------------------------------------------------------
__global__ __launch_bounds__(256) void mtl_all(
    const float* __restrict__ wts,      // (B, NA)
    const int*   __restrict__ label,    // (B,)
    const float* __restrict__ y,        // (B, 4, NA)
    const float* __restrict__ gt_R,     // (B, NA, 9)
    const float* __restrict__ anchors,  // (NA, 9)
    float*       __restrict__ out,      // [.., ang_err at 4+b]
    float*       __restrict__ l2p,      // (PBLK,)
    float*       __restrict__ lpp,      // (PBLK,)
    float*       __restrict__ crp)      // (PBLK,)
{
    __shared__ __align__(16) float sg[2][GRPF];        // 2 x 8640 B
    __shared__ float s_red[12];
    const int tid  = threadIdx.x;
    const int lane = tid & 63;
    const int wave = tid >> 6;
    const int a    = lane;

    // ---- anchors: per-lane row, loaded ONCE per block (L2-hot, 2 KB) ----
    float A0=0,A1=0,A2=0,A3=0,A4=0,A5=0,A6=0,A7=0,A8=0;
    if (a < NAc) {
        const float* Ar = anchors + a * 9;
        A0=Ar[0]; A1=Ar[1]; A2=Ar[2];
        A3=Ar[3]; A4=Ar[4]; A5=Ar[5];
        A6=Ar[6]; A7=Ar[7]; A8=Ar[8];
    }

    // ---- prologue: stage group g0 = blockIdx.x into buffer 0 ----
    int g = blockIdx.x;
    {
        stage_group_async(gt_R, g, sg[0], wave, lane);
        const float4* gb4 = (const float4*)(gt_R + (size_t)g * GRPF);
        if (tid < 28) ((float4*)sg[0])[512 + tid] = gb4[512 + tid];   // tail 448 B
    }
    int b   = g * BPB + wave;
    int lab = label[b];
    float w = -INFINITY, qw=0, qx=0, qy=0, qz=0;
    if (a < NAc) {
        w = wts[(size_t)b * NAc + a];
        const float* yb = y + (size_t)b * (4 * NAc) + a;
        qw = yb[0];  qx = yb[NAc];  qy = yb[2 * NAc];  qz = yb[3 * NAc];
    }
    __syncthreads();   // drains the async stage (vmcnt(0) before s_barrier)

    float l2acc = 0.0f, lpacc = 0.0f, cracc = 0.0f;

    #pragma unroll
    for (int it = 0; it < ITER; ++it) {
        const int cur = it & 1, nxt = cur ^ 1;
        const int gn  = g + PBLK;

        // ---- prefetch next group: issue ALL loads before compute ----
        float4 p2 = make_float4(0.f, 0.f, 0.f, 0.f);
        int   labn = 0;
        float wn = -INFINITY, qwn=0, qxn=0, qyn=0, qzn=0;
        if (it + 1 < ITER) {
            stage_group_async(gt_R, gn, sg[nxt], wave, lane);   // async -> LDS
            const float4* nb4 = (const float4*)(gt_R + (size_t)gn * GRPF);
            if (tid < 28) p2 = nb4[512 + tid];                  // tail, write late
            const int bn = gn * BPB + wave;
            labn = label[bn];
            if (a < NAc) {
                wn = wts[(size_t)bn * NAc + a];
                const float* yb = y + (size_t)bn * (4 * NAc) + a;
                qwn = yb[0];  qxn = yb[NAc];  qyn = yb[2 * NAc];  qzn = yb[3 * NAc];
            }
        }

        // ---- rotmat for pair (b, a) -- serves both l2 and ang_err ----
        float nq  = sqrtf(qw*qw + qx*qx + qy*qy + qz*qz);
        float inv = 1.0f / fmaxf(nq, 1e-8f);
        float pw = qw*inv, px = qx*inv, py = qy*inv, pz = qz*inv;
        float R00 = 1.0f - 2.0f*(py*py + pz*pz);
        float R01 = 2.0f*(px*py - pz*pw);
        float R02 = 2.0f*(px*pz + py*pw);
        float R10 = 2.0f*(px*py + pz*pw);
        float R11 = 1.0f - 2.0f*(px*px + pz*pz);
        float R12 = 2.0f*(py*pz - px*pw);
        float R20 = 2.0f*(px*pz - py*pw);
        float R21 = 2.0f*(py*pz + px*pw);
        float R22 = 1.0f - 2.0f*(px*px + py*py);

        // ---- masked Frobenius term (accumulated across groups) ----
        if (a < NAc) {
            const float* grow = sg[cur] + wave * ROWF + a * 9;
            float g0 = grow[0], g1 = grow[1], g2 = grow[2];
            float g3 = grow[3], g4 = grow[4], g5 = grow[5];
            float g6 = grow[6], g7 = grow[7], g8 = grow[8];
            float xb = 0.5f * (g0 + g4 + g8 - 1.0f);
            if (xb > COS_ONE) {
                float d0 = g0-R00, d1 = g1-R01, d2 = g2-R02;
                float d3 = g3-R10, d4 = g4-R11, d5 = g5-R12;
                float d6 = g6-R20, d7 = g7-R21, d8 = g8-R22;
                l2acc += d0*d0 + d1*d1 + d2*d2
                       + d3*d3 + d4*d4 + d5*d5
                       + d6*d6 + d7*d7 + d8*d8;
            }
        }

        // ---- softmax / argmax (first-index tie-break) ----
        float mv = w;
        int   mi = lane;
        for (int off = 32; off; off >>= 1) {
            float ov = __shfl_xor(mv, off, 64);
            int   oi = __shfl_xor(mi, off, 64);
            if (ov > mv || (ov == mv && oi < mi)) { mv = ov; mi = oi; }
        }
        float e  = (a < NAc) ? expf(w - mv) : 0.0f;
        float se = e;
        for (int off = 32; off; off >>= 1) se += __shfl_xor(se, off, 64);
        float lse  = mv + logf(se);
        float wlab = __shfl(w, lab, 64);

        lpacc += wlab - lse;                       // lane-uniform
        cracc += (mi == lab) ? 1.0f : 0.0f;        // lane-uniform

        // ---- ang_err: winning lane already holds rotmat + anchor row ----
        if (lane == mi) {
            float P00 = A0*R00 + A1*R10 + A2*R20;
            float P01 = A0*R01 + A1*R11 + A2*R21;
            float P02 = A0*R02 + A1*R12 + A2*R22;
            float P10 = A3*R00 + A4*R10 + A5*R20;
            float P11 = A3*R01 + A4*R11 + A5*R21;
            float P12 = A3*R02 + A4*R12 + A5*R22;
            float P20 = A6*R00 + A7*R10 + A8*R20;
            float P21 = A6*R01 + A7*R11 + A8*R21;
            float P22 = A6*R02 + A7*R12 + A8*R22;
            const float* tR = sg[cur] + wave * ROWF + 29 * 9;   // true_R from LDS
            float tr = P00*tR[0] + P01*tR[1] + P02*tR[2]
                     + P10*tR[3] + P11*tR[4] + P12*tR[5]
                     + P20*tR[6] + P21*tR[7] + P22*tR[8];
            float cx = 0.5f * (tr - 1.0f);
            cx = fminf(fmaxf(cx, -1.0f + 1e-7f), 1.0f - 1e-7f);
            out[4 + b] = acosf(cx);
        }

        // ---- late tail ds_write (T14 split), then the one barrier ----
        if (it + 1 < ITER) {
            if (tid < 28) ((float4*)sg[nxt])[512 + tid] = p2;
        }
        __syncthreads();   // drains async stage of sg[nxt] + orders dbuf reuse

        // ---- rotate to next group ----
        w = wn; qw = qwn; qx = qxn; qy = qyn; qz = qzn;
        lab = labn; g = gn; b = gn * BPB + wave;
    }

    // ---- one cross-wave reduction per block ----
    for (int off = 32; off; off >>= 1) l2acc += __shfl_xor(l2acc, off, 64);
    if (lane == 0) {
        s_red[wave]     = l2acc;
        s_red[4 + wave] = lpacc;
        s_red[8 + wave] = cracc;
    }
    __syncthreads();
    if (tid == 0) {
        l2p[blockIdx.x] = s_red[0] + s_red[1] + s_red[2]  + s_red[3];
        lpp[blockIdx.x] = s_red[4] + s_red[5] + s_red[6]  + s_red[7];
        crp[blockIdx.x] = s_red[8] + s_red[9] + s_red[10] + s_red[11];
    }
}

// ---------------------------------------------------------------------------
// Finalize: 2048 partials per array (24 KB total), float4 loads, double
// accumulation, deterministic shfl+LDS tree.
// ---------------------------------------------------------------------------
__global__ __launch_bounds__(256) void mtl_final(
    const float* __restrict__ l2p,
    const float* __restrict__ lpp,
    const float* __restrict__ crp,
    float*       __restrict__ out)
{
    const int tid  = threadIdx.x;
    const int lane = tid & 63;
    const int wave = tid >> 6;

    double l2 = 0.0, lp = 0.0, cr = 0.0;
    const float4* l2p4 = (const float4*)l2p;   // 2048/4 = 512
    const float4* lpp4 = (const float4*)lpp;
    const float4* crp4 = (const float4*)crp;
    for (int i = tid; i < PBLK / 4; i += 256) {
        float4 v = l2p4[i];
        l2 += (double)v.x + (double)v.y + (double)v.z + (double)v.w;
        float4 u = lpp4[i];
        lp += (double)u.x + (double)u.y + (double)u.z + (double)u.w;
        float4 c = crp4[i];
        cr += (double)c.x + (double)c.y + (double)c.z + (double)c.w;
    }

    for (int off = 32; off; off >>= 1) {
        l2 += __shfl_xor(l2, off, 64);
        lp += __shfl_xor(lp, off, 64);
        cr += __shfl_xor(cr, off, 64);
    }
    __shared__ double s_l2[4], s_lp[4], s_cr[4];
    if (lane == 0) { s_l2[wave] = l2; s_lp[wave] = lp; s_cr[wave] = cr; }
    __syncthreads();
    if (tid == 0) {
        double t2 = s_l2[0] + s_l2[1] + s_l2[2] + s_l2[3];
        double tp = s_lp[0] + s_lp[1] + s_lp[2] + s_lp[3];
        double tc = s_cr[0] + s_cr[1] + s_cr[2] + s_cr[3];
        float cls = (float)(-tp / (double)Bc);
        float l2s = (float)(10.0 * t2);      // W_LOSS * l2_loss
        out[0] = cls + l2s;                  // loss
        out[1] = cls;                        // cls_loss
        out[2] = l2s;                        // W_LOSS * l2_loss
        out[3] = (float)(tc / (double)Bc);   // r_acc
    }
}

extern "C" void kernel_launch(void* const* d_in, const int* in_sizes, int n_in,
                              void* d_out, int out_size, void* d_ws, size_t ws_size,
                              hipStream_t stream) {
    const float* wts     = (const float*)d_in[0];
    const int*   label   = (const int*)d_in[1];
    const float* y       = (const float*)d_in[2];
    const float* gt_R    = (const float*)d_in[3];
    const float* anchors = (const float*)d_in[4];
    float* out = (float*)d_out;

    float* l2p = (float*)d_ws;       // PBLK floats
    float* lpp = l2p + PBLK;         // PBLK floats
    float* crp = lpp + PBLK;         // PBLK floats  (24 KB total)

    mtl_all  <<<PBLK, 256, 0, stream>>>(wts, label, y, gt_R, anchors,
                                        out, l2p, lpp, crp);
    mtl_final<<<1, 256, 0, stream>>>(l2p, lpp, crp, out);
}